// Round 12
// baseline (307.812 us; speedup 1.0000x reference)
//
#include <hip/hip_runtime.h>
#include <hip/hip_bf16.h>
#include <math.h>

namespace {

constexpr int C = 128;  // channels
constexpr int K = 32;   // max degree

typedef float float4v __attribute__((ext_vector_type(4)));
typedef short short8v __attribute__((ext_vector_type(8)));   // 8 bf16 (4 VGPR)
typedef unsigned short ushort8v __attribute__((ext_vector_type(8)));
typedef int int2v __attribute__((ext_vector_type(2)));

__device__ __forceinline__ float bf2f(unsigned short u) {
    return __uint_as_float(((unsigned int)u) << 16);
}
__device__ __forceinline__ unsigned short f2bf(float x) {
    __hip_bfloat16 h = __float2bfloat16(x);
    return *(unsigned short*)&h;
}

// ---------------------------------------------------------------------------
// Kernel 0: invs[n] = 1/sqrt(1 + #valid neighbors). Side jobs: block 0 zeroes
// h1's padding row N, block 129 zeroes h2's padding row N (gathers clamp -1
// to row N); blocks 1..128 pre-split W1/W2 into hi/lo bf16 planes (used by
// the layer-1 GEMM; fused layer-2 splits in-block).
// ---------------------------------------------------------------------------
__global__ __launch_bounds__(256) void deg_kernel(
    const int* __restrict__ edge, float* __restrict__ invs,
    unsigned int* __restrict__ hz1, unsigned int* __restrict__ hz2,
    const float* __restrict__ W1, const float* __restrict__ W2,
    unsigned short* __restrict__ whl, int N) {
    const int bid = blockIdx.x;
    const int t = threadIdx.x;

    if (bid == 0 && t < 64) hz1[(size_t)N * (C / 2) + t] = 0u;
    if (bid == 129 && t < 64) hz2[(size_t)N * (C / 2) + t] = 0u;
    if (bid >= 1 && bid <= 128) {
        int which = (bid - 1) >> 6;           // 0: W1, 1: W2
        int p = ((bid - 1) & 63) * 256 + t;   // 0..16383
        float w = (which ? W2 : W1)[p];
        unsigned short hb = f2bf(w);
        unsigned short lb = f2bf(w - bf2f(hb));
        unsigned short* dst = whl + (size_t)which * 32768;
        dst[p] = hb;
        dst[16384 + p] = lb;
    }

    int node = bid * 32 + (t >> 3);
    int k4 = (t & 7) * 4;
    int4 e = make_int4(-1, -1, -1, -1);
    if (node < N) e = *(const int4*)(edge + (size_t)node * K + k4);
    int cnt = (e.x >= 0) + (e.y >= 0) + (e.z >= 0) + (e.w >= 0);
    cnt += __shfl_xor(cnt, 1);
    cnt += __shfl_xor(cnt, 2);
    cnt += __shfl_xor(cnt, 4);
    if ((t & 7) == 0 && node < N)
        invs[node] = 1.0f / sqrtf((float)(cnt + 1));
}

// ---------------------------------------------------------------------------
// Kernel 1: H[n][ch] = bf16( (X[n] . W[ch]) * invs[n] )   (round-11 proven)
// Split-bf16 MFMA GEMM, 3-term (fp32 A): pre-split W planes staged to LDS.
// ---------------------------------------------------------------------------
__global__ __launch_bounds__(256, 2) void gemm_mfma_kernel(
    const float* __restrict__ X, const unsigned short* __restrict__ Wp,
    const float* __restrict__ invs, unsigned short* __restrict__ H, int N) {
    __shared__ unsigned short Whl[2][C][136];

    const int t = threadIdx.x;
    const int n0 = blockIdx.x * 128;

    for (int p = t; p < 2 * C * 16; p += 256) {
        int seg = p >> 11;
        int rem = p & 2047;
        int row = rem >> 4;
        int v8 = (rem & 15) * 8;
        *(ushort8v*)&Whl[seg][row][v8] =
            *(const ushort8v*)(Wp + (size_t)seg * 16384 + row * 128 + v8);
    }
    __syncthreads();

    const int wv = t >> 6;
    const int l = t & 63;
    const int lm = l & 15;
    const int lk = l >> 4;
    const int rbase = n0 + wv * 32;

    int rowA0 = rbase + lm;
    int rowA1 = rbase + 16 + lm;
    rowA0 = rowA0 < N ? rowA0 : N - 1;
    rowA1 = rowA1 < N ? rowA1 : N - 1;
    const float* xp0 = X + (size_t)rowA0 * C;
    const float* xp1 = X + (size_t)rowA1 * C;

    float4v acc[2][8];
#pragma unroll
    for (int rt = 0; rt < 2; ++rt)
#pragma unroll
        for (int ct = 0; ct < 8; ++ct) acc[rt][ct] = {0.f, 0.f, 0.f, 0.f};

#pragma unroll
    for (int ks = 0; ks < 4; ++ks) {
        const int kb = ks * 32 + lk * 8;
        float xr0[8], xr1[8];
        *(float4v*)&xr0[0] = *(const float4v*)(xp0 + kb);
        *(float4v*)&xr0[4] = *(const float4v*)(xp0 + kb + 4);
        *(float4v*)&xr1[0] = *(const float4v*)(xp1 + kb);
        *(float4v*)&xr1[4] = *(const float4v*)(xp1 + kb + 4);
        short8v ah0, al0, ah1, al1;
#pragma unroll
        for (int j = 0; j < 8; ++j) {
            unsigned short h0 = f2bf(xr0[j]);
            unsigned short h1 = f2bf(xr1[j]);
            ah0[j] = (short)h0;
            ah1[j] = (short)h1;
            al0[j] = (short)f2bf(xr0[j] - bf2f(h0));
            al1[j] = (short)f2bf(xr1[j] - bf2f(h1));
        }
#pragma unroll
        for (int ct = 0; ct < 8; ++ct) {
            short8v bh = *(const short8v*)&Whl[0][ct * 16 + lm][kb];
            short8v bl = *(const short8v*)&Whl[1][ct * 16 + lm][kb];
            acc[0][ct] = __builtin_amdgcn_mfma_f32_16x16x32_bf16(ah0, bh,
                                                                 acc[0][ct], 0, 0, 0);
            acc[0][ct] = __builtin_amdgcn_mfma_f32_16x16x32_bf16(al0, bh,
                                                                 acc[0][ct], 0, 0, 0);
            acc[0][ct] = __builtin_amdgcn_mfma_f32_16x16x32_bf16(ah0, bl,
                                                                 acc[0][ct], 0, 0, 0);
            acc[1][ct] = __builtin_amdgcn_mfma_f32_16x16x32_bf16(ah1, bh,
                                                                 acc[1][ct], 0, 0, 0);
            acc[1][ct] = __builtin_amdgcn_mfma_f32_16x16x32_bf16(al1, bh,
                                                                 acc[1][ct], 0, 0, 0);
            acc[1][ct] = __builtin_amdgcn_mfma_f32_16x16x32_bf16(ah1, bl,
                                                                 acc[1][ct], 0, 0, 0);
        }
    }

    float sc[2][4];
#pragma unroll
    for (int rt = 0; rt < 2; ++rt)
#pragma unroll
        for (int q = 0; q < 4; ++q) {
            int r = rbase + rt * 16 + lk * 4 + q;
            sc[rt][q] = invs[r < N ? r : N - 1];
        }
#pragma unroll
    for (int rt = 0; rt < 2; ++rt)
#pragma unroll
        for (int ct = 0; ct < 8; ++ct)
#pragma unroll
            for (int q = 0; q < 4; ++q) {
                int r = rbase + rt * 16 + lk * 4 + q;
                if (r < N)
                    H[(size_t)r * C + ct * 16 + lm] =
                        f2bf(acc[rt][ct][q] * sc[rt][q]);
            }
}

// ---------------------------------------------------------------------------
// Kernel 2: canonical gather + ELU -> fp32 out (round-11 proven, ~108 us,
// at the random-gather L3-path roofline).
// ---------------------------------------------------------------------------
__global__ __launch_bounds__(256) void gather_elu_kernel(
    const unsigned short* __restrict__ H, const int* __restrict__ edge,
    const float* __restrict__ invs, float* __restrict__ out, int N) {
    __shared__ int idx_s[16][K];

    const int t = threadIdx.x;
    const int g = t >> 4;
    const int l16 = t & 15;
    const int node = blockIdx.x * 16 + g;

    {
        int p = t * 2;
        int r = p >> 5;
        int c0 = p & 31;
        int nn = blockIdx.x * 16 + r;
        int2v e = {-1, -1};
        if (nn < N) e = *(const int2v*)(edge + (size_t)nn * K + c0);
        idx_s[r][c0] = e.x;
        idx_s[r][c0 + 1] = e.y;
    }
    __syncthreads();
    if (node >= N) return;

    const unsigned short* hp = H + l16 * 8;
    float acc[8];
#pragma unroll
    for (int i = 0; i < 8; ++i) acc[i] = 0.f;

#pragma unroll
    for (int k0 = 0; k0 < K; k0 += 16) {
        ushort8v v[16];
#pragma unroll
        for (int u = 0; u < 16; ++u) {
            int j = idx_s[g][k0 + u];
            j = (j < 0) ? N : j;
            v[u] = *(const ushort8v*)(hp + (size_t)j * C);
        }
#pragma unroll
        for (int u = 0; u < 16; ++u)
#pragma unroll
            for (int i = 0; i < 8; ++i) acc[i] += bf2f(v[u][i]);
    }

    ushort8v sv = *(const ushort8v*)(hp + (size_t)node * C);
    float s = invs[node];
    float r[8];
#pragma unroll
    for (int i = 0; i < 8; ++i) {
        float x = (acc[i] + bf2f(sv[i])) * s;
        r[i] = x > 0.f ? x : expm1f(x);
    }
    float* dst = out + (size_t)node * C + l16 * 8;
    float4v lo = {r[0], r[1], r[2], r[3]};
    float4v hi = {r[4], r[5], r[6], r[7]};
    *(float4v*)dst = lo;
    *(float4v*)(dst + 4) = hi;
}

// ---------------------------------------------------------------------------
// Kernel 3 (NEW): fused gather(layer1) + GEMM(layer2).
// Per 16-node tile: gather h1 neighbor sums -> act = elu((sum+self)*invs) in
// fp32 regs -> round to bf16 (act is then EXACTLY bf16 => A-split lo term is
// 0, so 2-term MFMA suffices: a@W2h + a@W2l) -> stage act tile in LDS ->
// MFMA vs W2 (split in-block to hi/lo LDS planes) -> h2 = bf16(out * invs).
// Eliminates the 51+51 MB fp32 act round-trip and the separate gemm2
// dispatch; the MFMA rides in the gather's memory-wait shadow (round-11:
// VALUBusy 32%, MFMA pipe idle). LDS 76 KB -> 2 blocks/CU (~25% occ; wall
// was occupancy-insensitive 30-52%).
// ---------------------------------------------------------------------------
__global__ __launch_bounds__(256) void fused_gather_gemm_kernel(
    const unsigned short* __restrict__ H1, const int* __restrict__ edge,
    const float* __restrict__ invs, const float* __restrict__ W2,
    unsigned short* __restrict__ H2, int N) {
    __shared__ unsigned short Whl[2][C][136];   // 69.6 KB
    __shared__ unsigned short act_s[16][136];   // 4.3 KB
    __shared__ int idx_s[16][K];                // 2 KB

    const int t = threadIdx.x;
    const int base = blockIdx.x * 16;

    // Stage + split W2 (16384 floats; 16 float4/thread).
    for (int p = t; p < C * 32; p += 256) {
        int row = p >> 5;
        int c4 = (p & 31) * 4;
        float4 w = ((const float4*)W2)[p];
        float wv[4] = {w.x, w.y, w.z, w.w};
#pragma unroll
        for (int j = 0; j < 4; ++j) {
            unsigned short hb = f2bf(wv[j]);
            Whl[0][row][c4 + j] = hb;
            Whl[1][row][c4 + j] = f2bf(wv[j] - bf2f(hb));
        }
    }
    // Stage edges (16 nodes x 32).
    {
        int p = t * 2;
        int r = p >> 5;
        int c0 = p & 31;
        int nn = base + r;
        int2v e = {-1, -1};
        if (nn < N) e = *(const int2v*)(edge + (size_t)nn * K + c0);
        idx_s[r][c0] = e.x;
        idx_s[r][c0 + 1] = e.y;
    }
    __syncthreads();

    // ---- Gather phase (round-11 shape: 16 lanes/node, ushort8, batch 16).
    {
        const int g = t >> 4;
        const int l16 = t & 15;
        const int node = base + g;
        const unsigned short* hp = H1 + l16 * 8;
        float acc[8];
#pragma unroll
        for (int i = 0; i < 8; ++i) acc[i] = 0.f;

#pragma unroll
        for (int k0 = 0; k0 < K; k0 += 16) {
            ushort8v v[16];
#pragma unroll
            for (int u = 0; u < 16; ++u) {
                int j = idx_s[g][k0 + u];
                j = (j < 0) ? N : j;  // h1 row N is zeros
                v[u] = *(const ushort8v*)(hp + (size_t)j * C);
            }
#pragma unroll
            for (int u = 0; u < 16; ++u)
#pragma unroll
                for (int i = 0; i < 8; ++i) acc[i] += bf2f(v[u][i]);
        }

        ushort8v av = {0, 0, 0, 0, 0, 0, 0, 0};
        if (node < N) {
            ushort8v sv = *(const ushort8v*)(hp + (size_t)node * C);
            float s = invs[node];
#pragma unroll
            for (int i = 0; i < 8; ++i) {
                float x = (acc[i] + bf2f(sv[i])) * s;
                x = x > 0.f ? x : expm1f(x);
                av[i] = f2bf(x);
            }
        }
        *(ushort8v*)&act_s[g][l16 * 8] = av;
    }
    __syncthreads();

    // ---- MFMA phase: C[16 nodes][128 ch] = act @ W2^T, 2-term split-B.
    const int wv = t >> 6;  // wave -> col-tiles wv*2, wv*2+1
    const int l = t & 63;
    const int lm = l & 15;
    const int lk = l >> 4;

    float4v o[2] = {{0.f, 0.f, 0.f, 0.f}, {0.f, 0.f, 0.f, 0.f}};
#pragma unroll
    for (int ks = 0; ks < 4; ++ks) {
        const int kb = ks * 32 + lk * 8;
        short8v a = *(const short8v*)&act_s[lm][kb];
#pragma unroll
        for (int ci = 0; ci < 2; ++ci) {
            const int ct = wv * 2 + ci;
            short8v bh = *(const short8v*)&Whl[0][ct * 16 + lm][kb];
            short8v bl = *(const short8v*)&Whl[1][ct * 16 + lm][kb];
            o[ci] = __builtin_amdgcn_mfma_f32_16x16x32_bf16(a, bh, o[ci], 0, 0, 0);
            o[ci] = __builtin_amdgcn_mfma_f32_16x16x32_bf16(a, bl, o[ci], 0, 0, 0);
        }
    }

#pragma unroll
    for (int q = 0; q < 4; ++q) {
        const int nd = base + lk * 4 + q;
        if (nd < N) {
            float s = invs[nd];
#pragma unroll
            for (int ci = 0; ci < 2; ++ci) {
                H2[(size_t)nd * C + (wv * 2 + ci) * 16 + lm] =
                    f2bf(o[ci][q] * s);
            }
        }
    }
}

}  // namespace

extern "C" void kernel_launch(void* const* d_in, const int* in_sizes, int n_in,
                              void* d_out, int out_size, void* d_ws, size_t ws_size,
                              hipStream_t stream) {
    const float* x = (const float*)d_in[0];
    const int* edge = (const int*)d_in[1];
    const float* W1 = (const float*)d_in[2];
    const float* W2 = (const float*)d_in[3];
    float* out = (float*)d_out;
    const int N = in_sizes[0] / C;  // 100000

    char* ws = (char*)d_ws;
    const size_t invs_bytes = ((size_t)N * sizeof(float) + 255) & ~(size_t)255;
    const size_t h_bytes = (((size_t)(N + 1) * C * 2) + 255) & ~(size_t)255;
    const size_t whl_bytes = 2 * 2 * 16384 * sizeof(unsigned short);

    float* invs = (float*)ws;
    unsigned short* h1 = (unsigned short*)(ws + invs_bytes);

    const int degBlocks = (N + 31) / 32;
    const int gemmBlocks = (N + 127) / 128;
    const int gatherBlocks = (N + 15) / 16;

    if (ws_size >= invs_bytes + 2 * h_bytes + whl_bytes) {
        // ---- Primary: fused layer-boundary path.
        unsigned short* h2 = (unsigned short*)(ws + invs_bytes + h_bytes);
        unsigned short* whl = (unsigned short*)(ws + invs_bytes + 2 * h_bytes);

        deg_kernel<<<degBlocks, 256, 0, stream>>>(
            edge, invs, (unsigned int*)h1, (unsigned int*)h2, W1, W2, whl, N);
        gemm_mfma_kernel<<<gemmBlocks, 256, 0, stream>>>(x, whl, invs, h1, N);
        fused_gather_gemm_kernel<<<gatherBlocks, 256, 0, stream>>>(
            h1, edge, invs, W2, h2, N);
        gather_elu_kernel<<<gatherBlocks, 256, 0, stream>>>(h2, edge, invs, out, N);
    } else {
        // ---- Fallback: round-11 proven path (act fp32 in d_out).
        unsigned short* whl = (unsigned short*)(ws + invs_bytes + h_bytes);

        deg_kernel<<<degBlocks, 256, 0, stream>>>(
            edge, invs, (unsigned int*)h1, (unsigned int*)h1, W1, W2, whl, N);
        gemm_mfma_kernel<<<gemmBlocks, 256, 0, stream>>>(x, whl, invs, h1, N);
        gather_elu_kernel<<<gatherBlocks, 256, 0, stream>>>(h1, edge, invs, out, N);
        gemm_mfma_kernel<<<gemmBlocks, 256, 0, stream>>>(out, whl + 32768, invs,
                                                         h1, N);
        gather_elu_kernel<<<gatherBlocks, 256, 0, stream>>>(h1, edge, invs, out, N);
    }
}

// Round 13
// 279.752 us; speedup vs baseline: 1.1003x; 1.1003x over previous
//
#include <hip/hip_runtime.h>
#include <hip/hip_bf16.h>
#include <math.h>

namespace {

constexpr int C = 128;  // channels
constexpr int K = 32;   // max degree

typedef float float4v __attribute__((ext_vector_type(4)));
typedef short short8v __attribute__((ext_vector_type(8)));   // 8 bf16 (4 VGPR)
typedef unsigned short ushort8v __attribute__((ext_vector_type(8)));
typedef int int2v __attribute__((ext_vector_type(2)));

__device__ __forceinline__ float bf2f(unsigned short u) {
    return __uint_as_float(((unsigned int)u) << 16);
}
__device__ __forceinline__ unsigned short f2bf(float x) {
    __hip_bfloat16 h = __float2bfloat16(x);
    return *(unsigned short*)&h;
}

// ---------------------------------------------------------------------------
// Kernel 0: invs[n] = 1/sqrt(1 + #valid neighbors). Side jobs: block 0 zeroes
// h1's padding row N, block 129 zeroes h2's padding row N; blocks 1..128
// pre-split W1/W2 into hi/lo bf16 planes (whl), used by gemm1 (LDS staging)
// and by the fused kernel (per-wave B-fragments straight from L2).
// ---------------------------------------------------------------------------
__global__ __launch_bounds__(256) void deg_kernel(
    const int* __restrict__ edge, float* __restrict__ invs,
    unsigned int* __restrict__ hz1, unsigned int* __restrict__ hz2,
    const float* __restrict__ W1, const float* __restrict__ W2,
    unsigned short* __restrict__ whl, int N) {
    const int bid = blockIdx.x;
    const int t = threadIdx.x;

    if (bid == 0 && t < 64) hz1[(size_t)N * (C / 2) + t] = 0u;
    if (bid == 129 && t < 64) hz2[(size_t)N * (C / 2) + t] = 0u;
    if (bid >= 1 && bid <= 128) {
        int which = (bid - 1) >> 6;           // 0: W1, 1: W2
        int p = ((bid - 1) & 63) * 256 + t;   // 0..16383
        float w = (which ? W2 : W1)[p];
        unsigned short hb = f2bf(w);
        unsigned short lb = f2bf(w - bf2f(hb));
        unsigned short* dst = whl + (size_t)which * 32768;
        dst[p] = hb;
        dst[16384 + p] = lb;
    }

    int node = bid * 32 + (t >> 3);
    int k4 = (t & 7) * 4;
    int4 e = make_int4(-1, -1, -1, -1);
    if (node < N) e = *(const int4*)(edge + (size_t)node * K + k4);
    int cnt = (e.x >= 0) + (e.y >= 0) + (e.z >= 0) + (e.w >= 0);
    cnt += __shfl_xor(cnt, 1);
    cnt += __shfl_xor(cnt, 2);
    cnt += __shfl_xor(cnt, 4);
    if ((t & 7) == 0 && node < N)
        invs[node] = 1.0f / sqrtf((float)(cnt + 1));
}

// ---------------------------------------------------------------------------
// Kernel 1: H[n][ch] = bf16( (X[n] . W[ch]) * invs[n] )   (round-11 proven)
// Split-bf16 MFMA GEMM, 3-term (fp32 A): pre-split W planes staged to LDS.
// ---------------------------------------------------------------------------
__global__ __launch_bounds__(256, 2) void gemm_mfma_kernel(
    const float* __restrict__ X, const unsigned short* __restrict__ Wp,
    const float* __restrict__ invs, unsigned short* __restrict__ H, int N) {
    __shared__ unsigned short Whl[2][C][136];

    const int t = threadIdx.x;
    const int n0 = blockIdx.x * 128;

    for (int p = t; p < 2 * C * 16; p += 256) {
        int seg = p >> 11;
        int rem = p & 2047;
        int row = rem >> 4;
        int v8 = (rem & 15) * 8;
        *(ushort8v*)&Whl[seg][row][v8] =
            *(const ushort8v*)(Wp + (size_t)seg * 16384 + row * 128 + v8);
    }
    __syncthreads();

    const int wv = t >> 6;
    const int l = t & 63;
    const int lm = l & 15;
    const int lk = l >> 4;
    const int rbase = n0 + wv * 32;

    int rowA0 = rbase + lm;
    int rowA1 = rbase + 16 + lm;
    rowA0 = rowA0 < N ? rowA0 : N - 1;
    rowA1 = rowA1 < N ? rowA1 : N - 1;
    const float* xp0 = X + (size_t)rowA0 * C;
    const float* xp1 = X + (size_t)rowA1 * C;

    float4v acc[2][8];
#pragma unroll
    for (int rt = 0; rt < 2; ++rt)
#pragma unroll
        for (int ct = 0; ct < 8; ++ct) acc[rt][ct] = {0.f, 0.f, 0.f, 0.f};

#pragma unroll
    for (int ks = 0; ks < 4; ++ks) {
        const int kb = ks * 32 + lk * 8;
        float xr0[8], xr1[8];
        *(float4v*)&xr0[0] = *(const float4v*)(xp0 + kb);
        *(float4v*)&xr0[4] = *(const float4v*)(xp0 + kb + 4);
        *(float4v*)&xr1[0] = *(const float4v*)(xp1 + kb);
        *(float4v*)&xr1[4] = *(const float4v*)(xp1 + kb + 4);
        short8v ah0, al0, ah1, al1;
#pragma unroll
        for (int j = 0; j < 8; ++j) {
            unsigned short h0 = f2bf(xr0[j]);
            unsigned short h1 = f2bf(xr1[j]);
            ah0[j] = (short)h0;
            ah1[j] = (short)h1;
            al0[j] = (short)f2bf(xr0[j] - bf2f(h0));
            al1[j] = (short)f2bf(xr1[j] - bf2f(h1));
        }
#pragma unroll
        for (int ct = 0; ct < 8; ++ct) {
            short8v bh = *(const short8v*)&Whl[0][ct * 16 + lm][kb];
            short8v bl = *(const short8v*)&Whl[1][ct * 16 + lm][kb];
            acc[0][ct] = __builtin_amdgcn_mfma_f32_16x16x32_bf16(ah0, bh,
                                                                 acc[0][ct], 0, 0, 0);
            acc[0][ct] = __builtin_amdgcn_mfma_f32_16x16x32_bf16(al0, bh,
                                                                 acc[0][ct], 0, 0, 0);
            acc[0][ct] = __builtin_amdgcn_mfma_f32_16x16x32_bf16(ah0, bl,
                                                                 acc[0][ct], 0, 0, 0);
            acc[1][ct] = __builtin_amdgcn_mfma_f32_16x16x32_bf16(ah1, bh,
                                                                 acc[1][ct], 0, 0, 0);
            acc[1][ct] = __builtin_amdgcn_mfma_f32_16x16x32_bf16(al1, bh,
                                                                 acc[1][ct], 0, 0, 0);
            acc[1][ct] = __builtin_amdgcn_mfma_f32_16x16x32_bf16(ah1, bl,
                                                                 acc[1][ct], 0, 0, 0);
        }
    }

    float sc[2][4];
#pragma unroll
    for (int rt = 0; rt < 2; ++rt)
#pragma unroll
        for (int q = 0; q < 4; ++q) {
            int r = rbase + rt * 16 + lk * 4 + q;
            sc[rt][q] = invs[r < N ? r : N - 1];
        }
#pragma unroll
    for (int rt = 0; rt < 2; ++rt)
#pragma unroll
        for (int ct = 0; ct < 8; ++ct)
#pragma unroll
            for (int q = 0; q < 4; ++q) {
                int r = rbase + rt * 16 + lk * 4 + q;
                if (r < N)
                    H[(size_t)r * C + ct * 16 + lm] =
                        f2bf(acc[rt][ct][q] * sc[rt][q]);
            }
}

// ---------------------------------------------------------------------------
// Kernel 2: canonical gather + ELU -> fp32 out (round-11 proven, ~108 us,
// at the random-gather beyond-L2 roofline).
// ---------------------------------------------------------------------------
__global__ __launch_bounds__(256) void gather_elu_kernel(
    const unsigned short* __restrict__ H, const int* __restrict__ edge,
    const float* __restrict__ invs, float* __restrict__ out, int N) {
    __shared__ int idx_s[16][K];

    const int t = threadIdx.x;
    const int g = t >> 4;
    const int l16 = t & 15;
    const int node = blockIdx.x * 16 + g;

    {
        int p = t * 2;
        int r = p >> 5;
        int c0 = p & 31;
        int nn = blockIdx.x * 16 + r;
        int2v e = {-1, -1};
        if (nn < N) e = *(const int2v*)(edge + (size_t)nn * K + c0);
        idx_s[r][c0] = e.x;
        idx_s[r][c0 + 1] = e.y;
    }
    __syncthreads();
    if (node >= N) return;

    const unsigned short* hp = H + l16 * 8;
    float acc[8];
#pragma unroll
    for (int i = 0; i < 8; ++i) acc[i] = 0.f;

#pragma unroll
    for (int k0 = 0; k0 < K; k0 += 16) {
        ushort8v v[16];
#pragma unroll
        for (int u = 0; u < 16; ++u) {
            int j = idx_s[g][k0 + u];
            j = (j < 0) ? N : j;
            v[u] = *(const ushort8v*)(hp + (size_t)j * C);
        }
#pragma unroll
        for (int u = 0; u < 16; ++u)
#pragma unroll
            for (int i = 0; i < 8; ++i) acc[i] += bf2f(v[u][i]);
    }

    ushort8v sv = *(const ushort8v*)(hp + (size_t)node * C);
    float s = invs[node];
    float r[8];
#pragma unroll
    for (int i = 0; i < 8; ++i) {
        float x = (acc[i] + bf2f(sv[i])) * s;
        r[i] = x > 0.f ? x : expm1f(x);
    }
    float* dst = out + (size_t)node * C + l16 * 8;
    float4v lo = {r[0], r[1], r[2], r[3]};
    float4v hi = {r[4], r[5], r[6], r[7]};
    *(float4v*)dst = lo;
    *(float4v*)(dst + 4) = hi;
}

// ---------------------------------------------------------------------------
// Kernel 3 (v2): fused gather(layer1) + GEMM(layer2), 512 threads = 16 nodes.
// Round-12 failure causes fixed: (a) W2 planes NOT in LDS -- each wave's
// B-fragments (its 16-col slice, hi+lo, 32 VGPR/lane) load directly from the
// pre-split whl in global (128 KB, L2-hot); LDS is only act tile + edges
// (8.5 KB -> no LDS occupancy cap). (b) gather phase is the round-9 proven
// shape (32 lanes/node x ushort4, batch 16 => 32 VGPR in flight, VGPR~90
// total -> 4 waves/SIMD tier). act = elu(...) rounded to bf16 => exact bf16
// A => 2-term MFMA (a@W2h + a@W2l). h2 = bf16(o * invs).
// ---------------------------------------------------------------------------
__global__ __launch_bounds__(512) void fused_gather_gemm_kernel(
    const unsigned short* __restrict__ H1, const int* __restrict__ edge,
    const float* __restrict__ invs, const unsigned short* __restrict__ W2p,
    unsigned short* __restrict__ H2, int N) {
    __shared__ unsigned short act_s[16][136];  // 4.3 KB
    __shared__ int idx_s[16][K];               // 2 KB

    const int t = threadIdx.x;
    const int base = blockIdx.x * 16;

    // Stage edges: exactly 512 ints, 1/thread, coalesced.
    {
        int r = t >> 5, c0 = t & 31;
        int nn = base + r;
        idx_s[r][c0] = (nn < N) ? edge[(size_t)nn * K + c0] : -1;
    }

    // Per-wave B-fragments from pre-split W2 planes (global, L2-hot).
    const int wv = t >> 6;  // wave = col-tile ct (8 waves x 16 cols = 128)
    const int l = t & 63;
    const int lm = l & 15;
    const int lk = l >> 4;
    short8v bfrag[2][4];
#pragma unroll
    for (int pl = 0; pl < 2; ++pl)
#pragma unroll
        for (int ks = 0; ks < 4; ++ks)
            bfrag[pl][ks] = *(const short8v*)(W2p + (size_t)pl * 16384 +
                                              (wv * 16 + lm) * 128 + ks * 32 +
                                              lk * 8);

    __syncthreads();  // idx_s ready

    // ---- Gather phase (round-9 shape): 32 lanes/node, ushort4, batch 16.
    {
        const int g = t >> 5;
        const int lane32 = t & 31;
        const int node = base + g;
        const unsigned short* hp = H1 + lane32 * 4;
        float a0 = 0.f, a1 = 0.f, a2 = 0.f, a3 = 0.f;

#pragma unroll
        for (int k0 = 0; k0 < K; k0 += 16) {
            ushort4 v[16];
#pragma unroll
            for (int u = 0; u < 16; ++u) {
                int j = idx_s[g][k0 + u];
                j = (j < 0) ? N : j;  // h1 row N is zeros
                v[u] = *(const ushort4*)(hp + (size_t)j * C);
            }
#pragma unroll
            for (int u = 0; u < 16; ++u) {
                a0 += bf2f(v[u].x);
                a1 += bf2f(v[u].y);
                a2 += bf2f(v[u].z);
                a3 += bf2f(v[u].w);
            }
        }

        ushort4 av = {0, 0, 0, 0};
        if (node < N) {
            ushort4 sv = *(const ushort4*)(hp + (size_t)node * C);
            float s = invs[node];
            float x0 = (a0 + bf2f(sv.x)) * s;
            float x1 = (a1 + bf2f(sv.y)) * s;
            float x2 = (a2 + bf2f(sv.z)) * s;
            float x3 = (a3 + bf2f(sv.w)) * s;
            av.x = f2bf(x0 > 0.f ? x0 : expm1f(x0));
            av.y = f2bf(x1 > 0.f ? x1 : expm1f(x1));
            av.z = f2bf(x2 > 0.f ? x2 : expm1f(x2));
            av.w = f2bf(x3 > 0.f ? x3 : expm1f(x3));
        }
        *(ushort4*)&act_s[g][lane32 * 4] = av;
    }
    __syncthreads();

    // ---- MFMA phase: o[16 nodes][16 cols] per wave, 2-term split-B.
    float4v o = {0.f, 0.f, 0.f, 0.f};
#pragma unroll
    for (int ks = 0; ks < 4; ++ks) {
        short8v a = *(const short8v*)&act_s[lm][ks * 32 + lk * 8];
        o = __builtin_amdgcn_mfma_f32_16x16x32_bf16(a, bfrag[0][ks], o, 0, 0, 0);
        o = __builtin_amdgcn_mfma_f32_16x16x32_bf16(a, bfrag[1][ks], o, 0, 0, 0);
    }

#pragma unroll
    for (int q = 0; q < 4; ++q) {
        const int nd = base + lk * 4 + q;
        if (nd < N)
            H2[(size_t)nd * C + wv * 16 + lm] = f2bf(o[q] * invs[nd]);
    }
}

}  // namespace

extern "C" void kernel_launch(void* const* d_in, const int* in_sizes, int n_in,
                              void* d_out, int out_size, void* d_ws, size_t ws_size,
                              hipStream_t stream) {
    const float* x = (const float*)d_in[0];
    const int* edge = (const int*)d_in[1];
    const float* W1 = (const float*)d_in[2];
    const float* W2 = (const float*)d_in[3];
    float* out = (float*)d_out;
    const int N = in_sizes[0] / C;  // 100000

    char* ws = (char*)d_ws;
    const size_t invs_bytes = ((size_t)N * sizeof(float) + 255) & ~(size_t)255;
    const size_t h_bytes = (((size_t)(N + 1) * C * 2) + 255) & ~(size_t)255;
    const size_t whl_bytes = 2 * 2 * 16384 * sizeof(unsigned short);

    float* invs = (float*)ws;
    unsigned short* h1 = (unsigned short*)(ws + invs_bytes);

    const int degBlocks = (N + 31) / 32;
    const int gemmBlocks = (N + 127) / 128;
    const int gatherBlocks = (N + 15) / 16;

    if (ws_size >= invs_bytes + 2 * h_bytes + whl_bytes) {
        // ---- Primary: fused layer-boundary path.
        unsigned short* h2 = (unsigned short*)(ws + invs_bytes + h_bytes);
        unsigned short* whl = (unsigned short*)(ws + invs_bytes + 2 * h_bytes);

        deg_kernel<<<degBlocks, 256, 0, stream>>>(
            edge, invs, (unsigned int*)h1, (unsigned int*)h2, W1, W2, whl, N);
        gemm_mfma_kernel<<<gemmBlocks, 256, 0, stream>>>(x, whl, invs, h1, N);
        fused_gather_gemm_kernel<<<gatherBlocks, 512, 0, stream>>>(
            h1, edge, invs, whl + 32768, h2, N);
        gather_elu_kernel<<<gatherBlocks, 256, 0, stream>>>(h2, edge, invs, out, N);
    } else {
        // ---- Fallback: round-11 proven path (act fp32 in d_out).
        unsigned short* whl = (unsigned short*)(ws + invs_bytes + h_bytes);

        deg_kernel<<<degBlocks, 256, 0, stream>>>(
            edge, invs, (unsigned int*)h1, (unsigned int*)h1, W1, W2, whl, N);
        gemm_mfma_kernel<<<gemmBlocks, 256, 0, stream>>>(x, whl, invs, h1, N);
        gather_elu_kernel<<<gatherBlocks, 256, 0, stream>>>(h1, edge, invs, out, N);
        gemm_mfma_kernel<<<gemmBlocks, 256, 0, stream>>>(out, whl + 32768, invs,
                                                         h1, N);
        gather_elu_kernel<<<gatherBlocks, 256, 0, stream>>>(h1, edge, invs, out, N);
    }
}